// Round 14
// baseline (343.252 us; speedup 1.0000x reference)
//
#include <hip/hip_runtime.h>

#define HDIM 2048
#define HH (HDIM * HDIM)          // 4,194,304 = 2^22
#define NIDX 2000000
#define BINS 256
#define NCOPY 16
#define TL_BLOCKS 2048
#define NCHUNK 1000               // sort chunks: 2000 samples (500 int4) each
#define CH_I4 500
#define NWIN 128                  // window = pd>>15: 32K pixels

// workspace layout (bytes) — ~34 MB
#define PART_OFF   0                        // double partials[2048] = 16 KB
#define TAB_OFF    16384                    // float tab[3*BINS]
#define WGL_OFF    20480                    // uint Wg[2][129]
#define HIST_OFF   24576                    // uint hist[16][6][256] = 96 KB (memset)
#define CNT_D_OFF  131072                   // ushort cnt_d[1000][128] = 256 KB
#define CNT_R_OFF  393216
#define OFF_D_OFF  655360                   // uint off_d[1000][128] = 512 KB
#define OFF_R_OFF  1179648
#define CMAP_D_OFF 2097152                  // uchar cmap_d[HH] = 4 MB (count map / flags)
#define CMAP_R_OFF 6291456                  // uchar cmap_r[HH] = 4 MB
#define SORT_D_OFF 10485760                 // ushort sorted_d[NIDX] = 4 MB
#define SORT_R_OFF 14680064                 // ushort sorted_r[NIDX] = 4 MB
#define PD_OFF     18874368                 // int pd[NIDX] = 8 MB
#define PR_OFF     27262976                 // int pr[NIDX] = 8 MB (ends ~34 MB)

// Node 1: chunk-aligned flatten + per-chunk window counts (LDS only).
__global__ __launch_bounds__(256) void flat_kernel(
    const int* __restrict__ i0, const int* __restrict__ i1,
    const int* __restrict__ i2, const int* __restrict__ i3,
    int* __restrict__ pdArr, int* __restrict__ prArr,
    unsigned short* __restrict__ cnt_d, unsigned short* __restrict__ cnt_r)
{
    __shared__ unsigned cntd[NWIN], cntr[NWIN];
    const int b = blockIdx.x, t = threadIdx.x;
    for (int k = t; k < NWIN; k += 256) { cntd[k] = 0; cntr[k] = 0; }
    __syncthreads();

    for (int i = t; i < CH_I4; i += 256) {
        const int q = b * CH_I4 + i;
        const int4 a  = ((const int4*)i0)[q];
        const int4 bb = ((const int4*)i1)[q];
        const int4 c  = ((const int4*)i2)[q];
        const int4 d  = ((const int4*)i3)[q];
        const int4 pd4 = make_int4(a.x * HDIM + bb.x, a.y * HDIM + bb.y,
                                   a.z * HDIM + bb.z, a.w * HDIM + bb.w);
        const int4 pr4 = make_int4(c.x * HDIM + d.x, c.y * HDIM + d.y,
                                   c.z * HDIM + d.z, c.w * HDIM + d.w);
        ((int4*)pdArr)[q] = pd4;
        ((int4*)prArr)[q] = pr4;
        atomicAdd(&cntd[pd4.x >> 15], 1u); atomicAdd(&cntd[pd4.y >> 15], 1u);
        atomicAdd(&cntd[pd4.z >> 15], 1u); atomicAdd(&cntd[pd4.w >> 15], 1u);
        atomicAdd(&cntr[pr4.x >> 15], 1u); atomicAdd(&cntr[pr4.y >> 15], 1u);
        atomicAdd(&cntr[pr4.z >> 15], 1u); atomicAdd(&cntr[pr4.w >> 15], 1u);
    }
    __syncthreads();
    for (int k = t; k < NWIN; k += 256) {
        cnt_d[b * NWIN + k] = (unsigned short)cntd[k];
        cnt_r[b * NWIN + k] = (unsigned short)cntr[k];
    }
}

// Node 2: exact deterministic offsets (1 block, integer prefix sums).
__global__ __launch_bounds__(1024) void off_kernel(
    const unsigned short* __restrict__ cnt_d, const unsigned short* __restrict__ cnt_r,
    unsigned* __restrict__ off_d, unsigned* __restrict__ off_r, unsigned* __restrict__ Wg)
{
    __shared__ unsigned psum[8][NWIN], segbase[8][NWIN], wtot[NWIN], Wl[NWIN + 1];
    const int t = threadIdx.x;
    const int w = t & (NWIN - 1), seg = t >> 7;      // 8 segs x 125 chunks

    for (int side = 0; side < 2; side++) {
        const unsigned short* cnt = side ? cnt_r : cnt_d;
        unsigned* off = side ? off_r : off_d;
        unsigned s = 0;
        for (int b = seg * 125; b < seg * 125 + 125; b++) s += cnt[b * NWIN + w];
        psum[seg][w] = s;
        __syncthreads();
        if (t < NWIN) {
            unsigned run = 0;
            for (int sg = 0; sg < 8; sg++) { segbase[sg][t] = run; run += psum[sg][t]; }
            wtot[t] = run;
        }
        __syncthreads();
        if (t == 0) {
            unsigned run = 0;
            for (int w2 = 0; w2 < NWIN; w2++) { Wl[w2] = run; run += wtot[w2]; }
            Wl[NWIN] = run;                           // = NIDX
        }
        __syncthreads();
        unsigned run2 = Wl[w] + segbase[seg][w];
        for (int b = seg * 125; b < seg * 125 + 125; b++) {
            off[b * NWIN + w] = run2;
            run2 += cnt[b * NWIN + w];
        }
        if (t < NWIN + 1) Wg[side * (NWIN + 1) + t] = Wl[t];
        __syncthreads();
    }
}

// Node 3: place samples into exact sorted slots (LDS cursors; every slot
// written once; within-run order benign).
__global__ __launch_bounds__(256) void place_kernel(
    const int* __restrict__ pdArr, const int* __restrict__ prArr,
    const unsigned* __restrict__ off_d, const unsigned* __restrict__ off_r,
    unsigned short* __restrict__ sorted_d, unsigned short* __restrict__ sorted_r)
{
    __shared__ unsigned cur[NWIN];
    const int b = blockIdx.x, t = threadIdx.x;

    for (int k = t; k < NWIN; k += 256) cur[k] = off_d[b * NWIN + k];
    __syncthreads();
    for (int i = t; i < CH_I4; i += 256) {
        const int4 p4 = ((const int4*)pdArr)[b * CH_I4 + i];
        const int pd[4] = {p4.x, p4.y, p4.z, p4.w};
#pragma unroll
        for (int k = 0; k < 4; k++) {
            const unsigned pos = atomicAdd(&cur[pd[k] >> 15], 1u);
            sorted_d[pos] = (unsigned short)(pd[k] & 32767);
        }
    }
    __syncthreads();
    for (int k = t; k < NWIN; k += 256) cur[k] = off_r[b * NWIN + k];
    __syncthreads();
    for (int i = t; i < CH_I4; i += 256) {
        const int4 p4 = ((const int4*)prArr)[b * CH_I4 + i];
        const int pr[4] = {p4.x, p4.y, p4.z, p4.w};
#pragma unroll
        for (int k = 0; k < 4; k++) {
            const unsigned pos = atomicAdd(&cur[pr[k] >> 15], 1u);
            sorted_r[pos] = (unsigned short)(pr[k] & 32767);
        }
    }
}

// Node 4 (R14 new): window count-map BUILD -> global u8 maps. One block per
// (side, window): zero 32KB LDS map, scan the window's sorted entries ONCE
// (no quarter dup), sub-word LDS atomicAdd, then one coalesced 32KB store.
// 16 MB total traffic -> ~10us. If this shows ~40+us, the LDS-atomic build
// was the R12/R13 anomaly (diagnostic either way).
__global__ __launch_bounds__(256) void build_kernel(
    const unsigned short* __restrict__ sorted_d, const unsigned short* __restrict__ sorted_r,
    const unsigned* __restrict__ Wg,
    unsigned* __restrict__ cmap_d32, unsigned* __restrict__ cmap_r32)
{
    __shared__ unsigned cnt32[8192];        // u8[32768] count map, 32 KB
    const int b = blockIdx.x, t = threadIdx.x;
    const int side = b >> 7, win = b & (NWIN - 1);

    for (int k = t; k < 8192; k += 256) cnt32[k] = 0;
    __syncthreads();
    const unsigned e0 = Wg[side * (NWIN + 1) + win];
    const unsigned e1 = Wg[side * (NWIN + 1) + win + 1];
    const unsigned short* se = side ? sorted_r : sorted_d;
    for (unsigned e = e0 + t; e < e1; e += 256) {
        const unsigned lo = se[e];                   // 15-bit in-window offset
        atomicAdd(&cnt32[lo >> 2], 1u << ((lo & 3) * 8));
    }
    __syncthreads();
    unsigned* out = (side ? cmap_r32 : cmap_d32) + win * 8192;
    for (int k = t; k < 8192; k += 256) out[k] = cnt32[k];
}

// Node 5 (R14 new): pure STREAMING weighted histogram — grid-stride over all
// pixels (structure = R4's proven histpack; tabloss-like access pattern
// measured ~2.5 TB/s). Reads count maps + images + masks linearly; zero
// random access; zero window confinement. Bin-0 in registers; 16-copy flush.
__global__ __launch_bounds__(256) void sweep_kernel(
    const float* __restrict__ ref, const float* __restrict__ tgt,
    const float* __restrict__ msrc, const float* __restrict__ mtar,
    const unsigned* __restrict__ cmap_d32, const unsigned* __restrict__ cmap_r32,
    unsigned* __restrict__ hist)
{
    __shared__ unsigned lhist[6 * BINS];
    for (int k = threadIdx.x; k < 6 * BINS; k += 256) lhist[k] = 0;
    __syncthreads();

    unsigned z[6] = {0, 0, 0, 0, 0, 0};
    const int stride = gridDim.x * 256;
    for (int g = blockIdx.x * 256 + threadIdx.x; g < HH / 4; g += stride) {
        const unsigned cdw = cmap_d32[g];
        const unsigned crw = cmap_r32[g];
        const int p = g * 4;
        if (cdw) {
            const float4 m4 = *(const float4*)(msrc + p);
            const float4 v0 = *(const float4*)(ref + p);
            const float4 v1 = *(const float4*)(ref + HH + p);
            const float4 v2 = *(const float4*)(ref + 2 * HH + p);
            const float m[4]  = {m4.x, m4.y, m4.z, m4.w};
            const float a0[4] = {v0.x, v0.y, v0.z, v0.w};
            const float a1[4] = {v1.x, v1.y, v1.z, v1.w};
            const float a2[4] = {v2.x, v2.y, v2.z, v2.w};
#pragma unroll
            for (int k = 0; k < 4; k++) {
                const unsigned c = (cdw >> (k * 8)) & 255u;
                if (!c) continue;
                const float mm = m[k];
                // validated reference op order: ((x+1)*0.5)*255, then * mask
                const float f0 = ((a0[k] + 1.0f) * 0.5f) * 255.0f * mm;
                const float f1 = ((a1[k] + 1.0f) * 0.5f) * 255.0f * mm;
                const float f2 = ((a2[k] + 1.0f) * 0.5f) * 255.0f * mm;
                const unsigned b0 = (unsigned)(int)fminf(fmaxf(floorf(f0), 0.0f), 255.0f);
                const unsigned b1 = (unsigned)(int)fminf(fmaxf(floorf(f1), 0.0f), 255.0f);
                const unsigned b2 = (unsigned)(int)fminf(fmaxf(floorf(f2), 0.0f), 255.0f);
                if (b0) atomicAdd(&lhist[           b0], c); else z[0] += c;
                if (b1) atomicAdd(&lhist[1 * BINS + b1], c); else z[1] += c;
                if (b2) atomicAdd(&lhist[2 * BINS + b2], c); else z[2] += c;
            }
        }
        if (crw) {
            const float4 m4 = *(const float4*)(mtar + p);
            const float4 v0 = *(const float4*)(tgt + p);
            const float4 v1 = *(const float4*)(tgt + HH + p);
            const float4 v2 = *(const float4*)(tgt + 2 * HH + p);
            const float m[4]  = {m4.x, m4.y, m4.z, m4.w};
            const float a0[4] = {v0.x, v0.y, v0.z, v0.w};
            const float a1[4] = {v1.x, v1.y, v1.z, v1.w};
            const float a2[4] = {v2.x, v2.y, v2.z, v2.w};
#pragma unroll
            for (int k = 0; k < 4; k++) {
                const unsigned c = (crw >> (k * 8)) & 255u;
                if (!c) continue;
                const float mm = m[k];
                const float f0 = ((a0[k] + 1.0f) * 0.5f) * 255.0f * mm;
                const float f1 = ((a1[k] + 1.0f) * 0.5f) * 255.0f * mm;
                const float f2 = ((a2[k] + 1.0f) * 0.5f) * 255.0f * mm;
                const unsigned b0 = (unsigned)(int)fminf(fmaxf(floorf(f0), 0.0f), 255.0f);
                const unsigned b1 = (unsigned)(int)fminf(fmaxf(floorf(f1), 0.0f), 255.0f);
                const unsigned b2 = (unsigned)(int)fminf(fmaxf(floorf(f2), 0.0f), 255.0f);
                if (b0) atomicAdd(&lhist[3 * BINS + b0], c); else z[3] += c;
                if (b1) atomicAdd(&lhist[4 * BINS + b1], c); else z[4] += c;
                if (b2) atomicAdd(&lhist[5 * BINS + b2], c); else z[5] += c;
            }
        }
    }
#pragma unroll
    for (int c = 0; c < 6; c++)
        if (z[c]) atomicAdd(&lhist[c * BINS], z[c]);
    __syncthreads();
    unsigned* h = hist + (blockIdx.x & (NCOPY - 1)) * (6 * BINS);
    for (int k = threadIdx.x; k < 6 * BINS; k += 256) {
        const unsigned v = lhist[k];
        if (v) atomicAdd(&h[k], v);
    }
}

// Node 6: transfer table (1 block). Validated logic unchanged.
__global__ __launch_bounds__(256) void table_kernel(
    const unsigned* __restrict__ hist, float* __restrict__ tabg)
{
    __shared__ float    cdf[6 * BINS];
    __shared__ unsigned wsum[4];

    const int t    = threadIdx.x;
    const int lane = t & 63;
    const int wid  = t >> 6;

    for (int ch = 0; ch < 6; ch++) {
        unsigned x = 0;
#pragma unroll
        for (int cp = 0; cp < NCOPY; cp++) x += hist[cp * (6 * BINS) + ch * BINS + t];
#pragma unroll
        for (int d = 1; d < 64; d <<= 1) {
            const unsigned y = __shfl_up(x, d, 64);
            if (lane >= d) x += y;
        }
        if (lane == 63) wsum[wid] = x;
        __syncthreads();
        unsigned prefix = 0;
        for (int w = 0; w < wid; w++) prefix += wsum[w];
        x += prefix;
        cdf[ch * BINS + t] = (float)x / 2000000.0f;   // exact int < 2^24, single rounding
        __syncthreads();
    }
    for (int c = 0; c < 3; c++) {
        float o;
        if (t == 0)             o = 0.0f;
        else if (t == BINS - 1) o = 255.0f;
        else {
            const float v = cdf[c * BINS + t];
            const float* arr = cdf + (3 + c) * BINS;
            int lo = 0, hi = 256;   // lower_bound
            while (lo < hi) { const int mid = (lo + hi) >> 1; if (arr[mid] < v) lo = mid + 1; else hi = mid; }
            const int J0 = ((lo > 1) ? lo : 1) - 1;
            int lo2 = 0, hi2 = 256; // upper_bound
            while (lo2 < hi2) { const int mid = (lo2 + hi2) >> 1; if (arr[mid] <= v) lo2 = mid + 1; else hi2 = mid; }
            const int J1 = ((lo2 - 1) < 254 ? (lo2 - 1) : 254);
            const bool found = (lo2 >= 1) && (J0 <= J1);
            o = found ? (float)(J0 + 1) : (float)t;
        }
        tabg[c * BINS + t] = o;
    }
}

// Node 7: streaming loss. Sampled flag = cmap_d byte nonzero (R4 precedent —
// flags array deleted). Plain per-block partial store; stream-order visibility.
__global__ __launch_bounds__(256) void tabloss_kernel(
    const float* __restrict__ inp, const float* __restrict__ ref,
    const float* __restrict__ msrc, const float* __restrict__ tabg,
    const unsigned char* __restrict__ cmap_d, double* __restrict__ partials)
{
    __shared__ float  tab[3 * BINS];
    __shared__ double red[256];

    const int t = threadIdx.x;
    for (int k = t; k < 3 * BINS; k += 256) tab[k] = tabg[k];
    __syncthreads();

    double local = 0.0;
    const int stride = gridDim.x * 256;
    for (int g = blockIdx.x * 256 + t; g < HH / 4; g += stride) {
        const int p = g * 4;
        const float4 mv = *(const float4*)(msrc + p);
        const uchar4 fw = *(const uchar4*)(cmap_d + p);
        const unsigned samp[4] = {fw.x, fw.y, fw.z, fw.w};
        const float m[4] = {mv.x, mv.y, mv.z, mv.w};
#pragma unroll
        for (int c = 0; c < 3; c++) {
            const float4 rv = *(const float4*)(ref + c * HH + p);
            const float4 iv = *(const float4*)(inp + c * HH + p);
            const float r[4] = {rv.x, rv.y, rv.z, rv.w};
            const float x4[4] = {iv.x, iv.y, iv.z, iv.w};
            float s = 0.0f;
#pragma unroll
            for (int k = 0; k < 4; k++) {
                const float mm = m[k];
                const float refm = ((r[k] + 1.0f) * 0.5f) * 255.0f * mm;
                const float inpm = ((x4[k] + 1.0f) * 0.5f) * 255.0f * mm;
                float matchv;
                if (samp[k]) {
                    const int bidx = (int)fminf(fmaxf(refm, 0.0f), 255.0f);
                    matchv = tab[c * BINS + bidx];
                } else {
                    matchv = refm;
                }
                const float dd = inpm - matchv * mm;
                s += dd * dd;
            }
            local += (double)s;
        }
    }
    red[t] = local;
    __syncthreads();
    for (int s2 = 128; s2 > 0; s2 >>= 1) {
        if (t < s2) red[t] += red[t + s2];
        __syncthreads();
    }
    if (t == 0) partials[blockIdx.x] = red[0];
}

// Node 8: single-block finalize.
__global__ __launch_bounds__(256) void finalize_kernel(
    const double* __restrict__ partials, float* __restrict__ out)
{
    const int t = threadIdx.x;
    double s = 0.0;
    for (int k = t; k < TL_BLOCKS; k += 256) s += partials[k];
    __shared__ double red[256];
    red[t] = s;
    __syncthreads();
    for (int s2 = 128; s2 > 0; s2 >>= 1) {
        if (t < s2) red[t] += red[t + s2];
        __syncthreads();
    }
    if (t == 0) out[0] = (float)(red[0] / (double)(3 * HH));
}

extern "C" void kernel_launch(void* const* d_in, const int* in_sizes, int n_in,
                              void* d_out, int out_size, void* d_ws, size_t ws_size,
                              hipStream_t stream)
{
    const float* input_data  = (const float*)d_in[0];
    const float* target_data = (const float*)d_in[1];
    const float* mask_src    = (const float*)d_in[2];
    const float* mask_tar    = (const float*)d_in[3];
    const int*   i0          = (const int*)d_in[4];
    const int*   i1          = (const int*)d_in[5];
    const int*   i2          = (const int*)d_in[6];
    const int*   i3          = (const int*)d_in[7];
    const float* ref_data    = (const float*)d_in[8];
    float* out = (float*)d_out;

    char* ws = (char*)d_ws;
    double*         partials = (double*)(ws + PART_OFF);
    float*          tabg     = (float*)(ws + TAB_OFF);
    unsigned*       Wg       = (unsigned*)(ws + WGL_OFF);
    unsigned*       hist     = (unsigned*)(ws + HIST_OFF);
    unsigned short* cnt_d    = (unsigned short*)(ws + CNT_D_OFF);
    unsigned short* cnt_r    = (unsigned short*)(ws + CNT_R_OFF);
    unsigned*       off_d    = (unsigned*)(ws + OFF_D_OFF);
    unsigned*       off_r    = (unsigned*)(ws + OFF_R_OFF);
    unsigned*       cmap_d32 = (unsigned*)(ws + CMAP_D_OFF);
    unsigned*       cmap_r32 = (unsigned*)(ws + CMAP_R_OFF);
    const unsigned char* cmap_d = (const unsigned char*)(ws + CMAP_D_OFF);
    unsigned short* sorted_d = (unsigned short*)(ws + SORT_D_OFF);
    unsigned short* sorted_r = (unsigned short*)(ws + SORT_R_OFF);
    int*            pdArr    = (int*)(ws + PD_OFF);
    int*            prArr    = (int*)(ws + PR_OFF);

    hipMemsetAsync(ws + HIST_OFF, 0, NCOPY * 6 * BINS * 4, stream);
    flat_kernel<<<NCHUNK, 256, 0, stream>>>(i0, i1, i2, i3, pdArr, prArr, cnt_d, cnt_r);
    off_kernel<<<1, 1024, 0, stream>>>(cnt_d, cnt_r, off_d, off_r, Wg);
    place_kernel<<<NCHUNK, 256, 0, stream>>>(pdArr, prArr, off_d, off_r, sorted_d, sorted_r);
    build_kernel<<<2 * NWIN, 256, 0, stream>>>(sorted_d, sorted_r, Wg, cmap_d32, cmap_r32);
    sweep_kernel<<<2048, 256, 0, stream>>>(ref_data, target_data, mask_src, mask_tar,
                                           cmap_d32, cmap_r32, hist);
    table_kernel<<<1, 256, 0, stream>>>(hist, tabg);
    tabloss_kernel<<<TL_BLOCKS, 256, 0, stream>>>(input_data, ref_data, mask_src, tabg,
                                                  cmap_d, partials);
    finalize_kernel<<<1, 256, 0, stream>>>(partials, out);
}